// Round 3
// baseline (632.676 us; speedup 1.0000x reference)
//
#include <hip/hip_runtime.h>
#include <hip/hip_bf16.h>
#include <math.h>

#define Bn   16
#define Jn   2048
#define Hn   2048
#define OUTn 128
#define HDn  16

// proj tiling: block M=64 (j), N=160 (128 q + 16 v + 1 ksum + 15 zero), KC=64
#define KC      64
#define NCHUNK  (Hn / KC)          // 32
#define A_UNITS 512                // 64*64/8 units of 8 bf16 per plane
#define B_UNITS 1280               // 160*64/8 units per plane
#define WPK_CHUNK_BYTES (2 * B_UNITS * 16)   // 40960 B per chunk (hi+lo)

// workspace layout (floats)
#define WS_PART1 2048                        // [256][2048] col-sum partials
#define WS_WPK   (WS_PART1 + 256 * 2048)     // packed weights (uint4 region)
#define WS_PART  (WS_WPK + NCHUNK * 2 * B_UNITS * 4)  // [16][32][128][17] attn partials

typedef __attribute__((ext_vector_type(8))) short bf16x8_t;
typedef __attribute__((ext_vector_type(4))) float f32x4_t;

typedef __attribute__((address_space(1))) const void gvoid_t;
typedef __attribute__((address_space(3))) void lvoid_t;

__device__ __forceinline__ unsigned short f2bf(float x) {
  unsigned u = __builtin_bit_cast(unsigned, x);
  unsigned r = (u + 0x7fffu + ((u >> 16) & 1u)) >> 16;
  return (unsigned short)r;
}
__device__ __forceinline__ float bf2f(unsigned short h) {
  unsigned u = ((unsigned)h) << 16;
  return __builtin_bit_cast(float, u);
}

// -------- prep1: contention-free column-sum partials of wk_w ---------------
// blocks 0..255: part1[blk][c] = sum_{h in blk*8..+8} wk_w[h][c]
// block 256: ws[0] = sum(wk_b)
__global__ __launch_bounds__(256) void prep1_kernel(const float* __restrict__ wk_w,
                                                    const float* __restrict__ wk_b,
                                                    float* __restrict__ ws) {
  const int blk = blockIdx.x;
  const int tid = threadIdx.x;
  if (blk < 256) {
    const int h0 = blk * 8;
    const int c0 = tid * 8;
    float a[8] = {0.f, 0.f, 0.f, 0.f, 0.f, 0.f, 0.f, 0.f};
#pragma unroll
    for (int h = 0; h < 8; ++h) {
      const float* row = wk_w + (size_t)(h0 + h) * Hn + c0;
      const float4 u = *(const float4*)row;
      const float4 v = *(const float4*)(row + 4);
      a[0] += u.x; a[1] += u.y; a[2] += u.z; a[3] += u.w;
      a[4] += v.x; a[5] += v.y; a[6] += v.z; a[7] += v.w;
    }
    float* dst = ws + WS_PART1 + (size_t)blk * Hn + c0;
    *(float4*)dst       = make_float4(a[0], a[1], a[2], a[3]);
    *(float4*)(dst + 4) = make_float4(a[4], a[5], a[6], a[7]);
  } else {
    __shared__ float red[256];
    float s = 0.f;
    for (int h = tid; h < Hn; h += 256) s += wk_b[h];
    red[tid] = s;
    __syncthreads();
    for (int off = 128; off > 0; off >>= 1) {
      if (tid < off) red[tid] += red[tid + off];
      __syncthreads();
    }
    if (tid == 0) ws[0] = red[0];
  }
}

// -------- prep2: pack weights into split-bf16, MFMA-tile-linear stream ------
// Row map: n<128 -> wq_w[n], n<144 -> wv_w[n-128], n==144 -> wksum, else 0.
__global__ __launch_bounds__(256) void prep2_kernel(const float* __restrict__ wq_w,
                                                    const float* __restrict__ wv_w,
                                                    const float* __restrict__ ws,
                                                    uint4* __restrict__ wpk) {
  const int id = blockIdx.x * 256 + threadIdx.x;     // 0 .. 40959
  const int chunk = id / B_UNITS;
  const int u     = id % B_UNITS;
  const int kblk  = u / 640;
  const int u2    = u % 640;
  const int nt    = u2 >> 6;
  const int g     = (u2 >> 4) & 3;
  const int n16   = u2 & 15;
  const int n     = nt * 16 + n16;
  const int k     = chunk * KC + kblk * 32 + g * 8;

  float x[8];
  if (n < OUTn) {
    const float* s = wq_w + (size_t)n * Hn + k;
#pragma unroll
    for (int i = 0; i < 8; ++i) x[i] = s[i];
  } else if (n < OUTn + HDn) {
    const float* s = wv_w + (size_t)(n - OUTn) * Hn + k;
#pragma unroll
    for (int i = 0; i < 8; ++i) x[i] = s[i];
  } else if (n == OUTn + HDn) {
    // wksum[k..k+8) = sum over 256 row-strip partials
#pragma unroll
    for (int i = 0; i < 8; ++i) x[i] = 0.f;
    const float* p1 = ws + WS_PART1 + k;
    for (int p = 0; p < 256; ++p) {
      const float4 a = *(const float4*)p1;
      const float4 b = *(const float4*)(p1 + 4);
      x[0] += a.x; x[1] += a.y; x[2] += a.z; x[3] += a.w;
      x[4] += b.x; x[5] += b.y; x[6] += b.z; x[7] += b.w;
      p1 += Hn;
    }
  } else {
#pragma unroll
    for (int i = 0; i < 8; ++i) x[i] = 0.f;
  }

  unsigned short hi[8], lo[8];
#pragma unroll
  for (int i = 0; i < 8; ++i) {
    hi[i] = f2bf(x[i]);
    lo[i] = f2bf(x[i] - bf2f(hi[i]));
  }
  uint4 uh, ul;
  uh.x = (unsigned)hi[0] | ((unsigned)hi[1] << 16);
  uh.y = (unsigned)hi[2] | ((unsigned)hi[3] << 16);
  uh.z = (unsigned)hi[4] | ((unsigned)hi[5] << 16);
  uh.w = (unsigned)hi[6] | ((unsigned)hi[7] << 16);
  ul.x = (unsigned)lo[0] | ((unsigned)lo[1] << 16);
  ul.y = (unsigned)lo[2] | ((unsigned)lo[3] << 16);
  ul.z = (unsigned)lo[4] | ((unsigned)lo[5] << 16);
  ul.w = (unsigned)lo[6] | ((unsigned)lo[7] << 16);
  wpk[(size_t)(chunk * 2 + 0) * B_UNITS + u] = uh;
  wpk[(size_t)(chunk * 2 + 1) * B_UNITS + u] = ul;
}

// -------- proj: split-bf16 MFMA GEMM + fused attention partials --------------
__global__ __launch_bounds__(256, 2) void proj_kernel(
    const float* __restrict__ vec,
    const float* __restrict__ wq_b,
    const float* __restrict__ wv_b,
    const float* __restrict__ wsc,     // ws[0] = wkb sum
    const uint4* __restrict__ wpk,     // packed split-bf16 weights
    float* __restrict__ part)          // [B][32][128][17] attn partials
{
  __shared__ uint4 As[2 * A_UNITS];    // hi then lo, 16 KB
  __shared__ uint4 Bs[2 * B_UNITS];    // hi then lo, 40 KB

  const int tid   = threadIdx.x;
  const int lane  = tid & 63;
  const int w     = tid >> 6;          // wave 0..3
  const int wm    = w >> 1;            // wave M half (0/1): rows wm*32..+31
  const int wn    = w & 1;             // wave N half: ntiles wn*5..+4
  const int b     = blockIdx.x >> 5;
  const int jt    = blockIdx.x & 31;
  const int j0    = jt * 64;
  const int col16 = lane & 15;
  const int rbase = (lane >> 4) * 4;

  const float* vecb = vec + (size_t)b * Jn * Hn;
  const bf16x8_t* As8 = (const bf16x8_t*)As;
  const bf16x8_t* Bs8 = (const bf16x8_t*)Bs;

  f32x4_t acc[2][5];
#pragma unroll
  for (int mi = 0; mi < 2; ++mi)
#pragma unroll
    for (int ni = 0; ni < 5; ++ni) acc[mi][ni] = (f32x4_t){0.f, 0.f, 0.f, 0.f};

  for (int chunk = 0; chunk < NCHUNK; ++chunk) {
    const int k0 = chunk * KC;
    // ---- stage A: 2 units/thread, each = 8 consecutive fp32 -> hi+lo bf16x8
#pragma unroll
    for (int rep = 0; rep < 2; ++rep) {
      const int u    = tid + rep * 256;       // 0..511
      const int kblk = u >> 8;
      const int mt   = (u >> 6) & 3;
      const int g    = (u >> 4) & 3;
      const int m    = u & 15;
      const float* src = vecb + (size_t)(j0 + mt * 16 + m) * Hn + k0 + kblk * 32 + g * 8;
      const float4 a0 = *(const float4*)src;
      const float4 a1 = *(const float4*)(src + 4);
      float x[8] = {a0.x, a0.y, a0.z, a0.w, a1.x, a1.y, a1.z, a1.w};
      unsigned short hi[8], lo[8];
#pragma unroll
      for (int i = 0; i < 8; ++i) {
        hi[i] = f2bf(x[i]);
        lo[i] = f2bf(x[i] - bf2f(hi[i]));
      }
      uint4 uh, ul;
      uh.x = (unsigned)hi[0] | ((unsigned)hi[1] << 16);
      uh.y = (unsigned)hi[2] | ((unsigned)hi[3] << 16);
      uh.z = (unsigned)hi[4] | ((unsigned)hi[5] << 16);
      uh.w = (unsigned)hi[6] | ((unsigned)hi[7] << 16);
      ul.x = (unsigned)lo[0] | ((unsigned)lo[1] << 16);
      ul.y = (unsigned)lo[2] | ((unsigned)lo[3] << 16);
      ul.z = (unsigned)lo[4] | ((unsigned)lo[5] << 16);
      ul.w = (unsigned)lo[6] | ((unsigned)lo[7] << 16);
      As[u]           = uh;
      As[A_UNITS + u] = ul;
    }
    // ---- stage B: async global->LDS, 16B/lane, pre-packed linear stream
    {
      const char* gbase = (const char*)wpk + (size_t)chunk * WPK_CHUNK_BYTES + (size_t)lane * 16;
#pragma unroll
      for (int i = 0; i < 10; ++i) {
        const int q = w + i * 4;               // 0..39 wave-instrs of 1 KB
        __builtin_amdgcn_global_load_lds((gvoid_t*)(gbase + q * 1024),
                                         (lvoid_t*)&Bs[q * 64], 16, 0, 0);
      }
    }
    __syncthreads();

#pragma unroll
    for (int kblk = 0; kblk < 2; ++kblk) {
      bf16x8_t bh[5], bl[5];
#pragma unroll
      for (int ni = 0; ni < 5; ++ni) {
        const int idx = (kblk * 10 + wn * 5 + ni) * 64 + lane;
        bh[ni] = Bs8[idx];
        bl[ni] = Bs8[B_UNITS + idx];
      }
#pragma unroll
      for (int mi = 0; mi < 2; ++mi) {
        const int aidx = (kblk * 4 + wm * 2 + mi) * 64 + lane;
        const bf16x8_t ah = As8[aidx];
        const bf16x8_t al = As8[A_UNITS + aidx];
#pragma unroll
        for (int ni = 0; ni < 5; ++ni) {
          acc[mi][ni] = __builtin_amdgcn_mfma_f32_16x16x32_bf16(ah, bh[ni], acc[mi][ni], 0, 0, 0);
          acc[mi][ni] = __builtin_amdgcn_mfma_f32_16x16x32_bf16(ah, bl[ni], acc[mi][ni], 0, 0, 0);
          acc[mi][ni] = __builtin_amdgcn_mfma_f32_16x16x32_bf16(al, bh[ni], acc[mi][ni], 0, 0, 0);
        }
      }
    }
    __syncthreads();
  }

  // ==== fused attention epilogue ====
  // C/D layout: col=lane&15, row=(lane>>4)*4+reg. Reuse As for ks/v staging,
  // Bs for the cross-wave [128][18] accumulator.
  const float wkb = wsc[0];
  float* ks_s = (float*)&As[0];          // [64]
  float* vt   = ks_s + 64;               // [64][20], rows 16B-aligned (80 B)
  float* epi  = (float*)&Bs[0];          // [128][18]

  if (wn == 1) {
    const float vb_ = wv_b[col16];
#pragma unroll
    for (int mi = 0; mi < 2; ++mi) {
      const f32x4_t c = acc[mi][3];      // v columns: n = 128 + col16
#pragma unroll
      for (int r = 0; r < 4; ++r) {
        const int j = (wm * 2 + mi) * 16 + rbase + r;
        vt[j * 20 + col16] = c[r] + vb_;
      }
    }
    if (col16 == 0) {
#pragma unroll
      for (int mi = 0; mi < 2; ++mi) {
        const f32x4_t c = acc[mi][4];    // ksum column: n = 144
#pragma unroll
        for (int r = 0; r < 4; ++r) {
          const int j = (wm * 2 + mi) * 16 + rbase + r;
          ks_s[j] = c[r] + wkb;
        }
      }
    }
  }
  __syncthreads();

  const int NCOL = wn ? 3 : 5;           // q columns this wave owns
  float qb[5];
  for (int ni = 0; ni < NCOL; ++ni) qb[ni] = wq_b[(wn * 5 + ni) * 16 + col16];

  float pz[5] = {0.f, 0.f, 0.f, 0.f, 0.f};
  float po[5][16];
#pragma unroll
  for (int ni = 0; ni < 5; ++ni)
#pragma unroll
    for (int d = 0; d < 16; ++d) po[ni][d] = 0.f;

#pragma unroll
  for (int mi = 0; mi < 2; ++mi) {
#pragma unroll
    for (int r = 0; r < 4; ++r) {
      const int j = (wm * 2 + mi) * 16 + rbase + r;
      const float ksj = ks_s[j];
      const float4 v0 = *(const float4*)&vt[j * 20];
      const float4 v1 = *(const float4*)&vt[j * 20 + 4];
      const float4 v2 = *(const float4*)&vt[j * 20 + 8];
      const float4 v3 = *(const float4*)&vt[j * 20 + 12];
      for (int ni = 0; ni < NCOL; ++ni) {
        const float q   = acc[mi][ni][r] + qb[ni];
        const float e2x = __expf(2.f * q * ksj);
        const float t   = 1.f - 2.f / (e2x + 1.f);
        const float p   = __expf(t);
        pz[ni] += p;
        po[ni][0]  += p * v0.x; po[ni][1]  += p * v0.y; po[ni][2]  += p * v0.z; po[ni][3]  += p * v0.w;
        po[ni][4]  += p * v1.x; po[ni][5]  += p * v1.y; po[ni][6]  += p * v1.z; po[ni][7]  += p * v1.w;
        po[ni][8]  += p * v2.x; po[ni][9]  += p * v2.y; po[ni][10] += p * v2.z; po[ni][11] += p * v2.w;
        po[ni][12] += p * v3.x; po[ni][13] += p * v3.y; po[ni][14] += p * v3.z; po[ni][15] += p * v3.w;
      }
    }
  }
  // reduce across lane bits 4,5 (the 4 rbase groups -> full 32-j wave half)
  for (int ni = 0; ni < NCOL; ++ni) {
    pz[ni] += __shfl_xor(pz[ni], 16);
    pz[ni] += __shfl_xor(pz[ni], 32);
#pragma unroll
    for (int d = 0; d < 16; ++d) {
      po[ni][d] += __shfl_xor(po[ni][d], 16);
      po[ni][d] += __shfl_xor(po[ni][d], 32);
    }
  }
  // cross-wm combine via LDS
  if (wm == 0 && lane < 16) {
    for (int ni = 0; ni < NCOL; ++ni) {
      const int n = (wn * 5 + ni) * 16 + lane;
      epi[n * 18 + 16] = pz[ni];
#pragma unroll
      for (int d = 0; d < 16; ++d) epi[n * 18 + d] = po[ni][d];
    }
  }
  __syncthreads();
  if (wm == 1 && lane < 16) {
    for (int ni = 0; ni < NCOL; ++ni) {
      const int n = (wn * 5 + ni) * 16 + lane;
      epi[n * 18 + 16] += pz[ni];
#pragma unroll
      for (int d = 0; d < 16; ++d) epi[n * 18 + d] += po[ni][d];
    }
  }
  __syncthreads();
  // coalesced store of [128][17] partial slab
  float* pout = part + ((size_t)(b * 32 + jt) * 128) * 17;
  for (int idx = tid; idx < 128 * 17; idx += 256)
    pout[idx] = epi[(idx / 17) * 18 + (idx % 17)];
}

// -------- finalize: out[b,i,d] = sum_jt O / sum_jt Z ------------------------
__global__ __launch_bounds__(256) void finalize_kernel(const float* __restrict__ part,
                                                       float* __restrict__ out) {
  const int gid = blockIdx.x * 256 + threadIdx.x;   // 0..2047 = (b,i)
  const float* p = part + (size_t)(gid >> 7) * 32 * 128 * 17 + (size_t)(gid & 127) * 17;
  float z = 0.f;
  float o[16];
#pragma unroll
  for (int d = 0; d < 16; ++d) o[d] = 0.f;
  for (int jt = 0; jt < 32; ++jt) {
    const float* pp = p + (size_t)jt * 128 * 17;
    z += pp[16];
#pragma unroll
    for (int d = 0; d < 16; ++d) o[d] += pp[d];
  }
  const float inv = 1.f / z;
  float* dst = out + (size_t)gid * 16;
#pragma unroll
  for (int d = 0; d < 16; ++d) dst[d] = o[d] * inv;
}

// ---------------------------------------------------------------------------
extern "C" void kernel_launch(void* const* d_in, const int* in_sizes, int n_in,
                              void* d_out, int out_size, void* d_ws, size_t ws_size,
                              hipStream_t stream) {
  const float* vec  = (const float*)d_in[0];
  const float* wq_w = (const float*)d_in[1];
  const float* wq_b = (const float*)d_in[2];
  const float* wk_w = (const float*)d_in[3];
  const float* wk_b = (const float*)d_in[4];
  const float* wv_w = (const float*)d_in[5];
  const float* wv_b = (const float*)d_in[6];

  float* ws   = (float*)d_ws;
  uint4* wpk  = (uint4*)(ws + WS_WPK);
  float* part = ws + WS_PART;
  float* out  = (float*)d_out;

  prep1_kernel<<<257, 256, 0, stream>>>(wk_w, wk_b, ws);
  prep2_kernel<<<(NCHUNK * B_UNITS) / 256, 256, 0, stream>>>(wq_w, wv_w, ws, wpk);
  proj_kernel<<<Bn * (Jn / 64), 256, 0, stream>>>(vec, wq_b, wv_b, ws, wpk, part);
  finalize_kernel<<<8, 256, 0, stream>>>(part, out);
}

// Round 4
// 448.859 us; speedup vs baseline: 1.4095x; 1.4095x over previous
//
#include <hip/hip_runtime.h>
#include <hip/hip_bf16.h>
#include <math.h>

#define Bn   16
#define Jn   2048
#define Hn   2048
#define OUTn 128
#define HDn  16

// proj tiling: block M=64 (j), N=160 (128 q + 16 v + 1 ksum + 15 zero), KC=64
#define KC      64
#define NCHUNK  (Hn / KC)          // 32
#define A_UNITS 512                // 64*64/8 units of 8 bf16 per plane
#define B_UNITS 1280               // 160*64/8 units per plane
#define WPK_CHUNK_BYTES (2 * B_UNITS * 16)   // 40960 B per chunk (hi+lo)

// workspace layout (floats)
#define WS_PART1 2048                        // [256][2048] col-sum partials
#define WS_WPK   (WS_PART1 + 256 * 2048)     // packed weights (uint4 region)
#define WS_PART  (WS_WPK + NCHUNK * 2 * B_UNITS * 4)  // [16][32][128][17] attn partials

typedef __attribute__((ext_vector_type(8))) short bf16x8_t;
typedef __attribute__((ext_vector_type(4))) float f32x4_t;

typedef __attribute__((address_space(1))) const void gvoid_t;
typedef __attribute__((address_space(3))) void lvoid_t;

__device__ __forceinline__ unsigned short f2bf(float x) {
  unsigned u = __builtin_bit_cast(unsigned, x);
  unsigned r = (u + 0x7fffu + ((u >> 16) & 1u)) >> 16;
  return (unsigned short)r;
}
__device__ __forceinline__ float bf2f(unsigned short h) {
  unsigned u = ((unsigned)h) << 16;
  return __builtin_bit_cast(float, u);
}

// -------- prep1: contention-free column-sum partials of wk_w ---------------
__global__ __launch_bounds__(256) void prep1_kernel(const float* __restrict__ wk_w,
                                                    const float* __restrict__ wk_b,
                                                    float* __restrict__ ws) {
  const int blk = blockIdx.x;
  const int tid = threadIdx.x;
  if (blk < 256) {
    const int h0 = blk * 8;
    const int c0 = tid * 8;
    float a[8] = {0.f, 0.f, 0.f, 0.f, 0.f, 0.f, 0.f, 0.f};
#pragma unroll
    for (int h = 0; h < 8; ++h) {
      const float* row = wk_w + (size_t)(h0 + h) * Hn + c0;
      const float4 u = *(const float4*)row;
      const float4 v = *(const float4*)(row + 4);
      a[0] += u.x; a[1] += u.y; a[2] += u.z; a[3] += u.w;
      a[4] += v.x; a[5] += v.y; a[6] += v.z; a[7] += v.w;
    }
    float* dst = ws + WS_PART1 + (size_t)blk * Hn + c0;
    *(float4*)dst       = make_float4(a[0], a[1], a[2], a[3]);
    *(float4*)(dst + 4) = make_float4(a[4], a[5], a[6], a[7]);
  } else {
    __shared__ float red[256];
    float s = 0.f;
    for (int h = tid; h < Hn; h += 256) s += wk_b[h];
    red[tid] = s;
    __syncthreads();
    for (int off = 128; off > 0; off >>= 1) {
      if (tid < off) red[tid] += red[tid + off];
      __syncthreads();
    }
    if (tid == 0) ws[0] = red[0];
  }
}

// -------- prep2: pack weights into split-bf16, MFMA-tile-linear stream ------
__global__ __launch_bounds__(256) void prep2_kernel(const float* __restrict__ wq_w,
                                                    const float* __restrict__ wv_w,
                                                    const float* __restrict__ ws,
                                                    uint4* __restrict__ wpk) {
  const int id = blockIdx.x * 256 + threadIdx.x;     // 0 .. 40959
  const int chunk = id / B_UNITS;
  const int u     = id % B_UNITS;
  const int kblk  = u / 640;
  const int u2    = u % 640;
  const int nt    = u2 >> 6;
  const int g     = (u2 >> 4) & 3;
  const int n16   = u2 & 15;
  const int n     = nt * 16 + n16;
  const int k     = chunk * KC + kblk * 32 + g * 8;

  float x[8];
  if (n < OUTn) {
    const float* s = wq_w + (size_t)n * Hn + k;
#pragma unroll
    for (int i = 0; i < 8; ++i) x[i] = s[i];
  } else if (n < OUTn + HDn) {
    const float* s = wv_w + (size_t)(n - OUTn) * Hn + k;
#pragma unroll
    for (int i = 0; i < 8; ++i) x[i] = s[i];
  } else if (n == OUTn + HDn) {
#pragma unroll
    for (int i = 0; i < 8; ++i) x[i] = 0.f;
    const float* p1 = ws + WS_PART1 + k;
    for (int p = 0; p < 256; ++p) {
      const float4 a = *(const float4*)p1;
      const float4 b = *(const float4*)(p1 + 4);
      x[0] += a.x; x[1] += a.y; x[2] += a.z; x[3] += a.w;
      x[4] += b.x; x[5] += b.y; x[6] += b.z; x[7] += b.w;
      p1 += Hn;
    }
  } else {
#pragma unroll
    for (int i = 0; i < 8; ++i) x[i] = 0.f;
  }

  unsigned short hi[8], lo[8];
#pragma unroll
  for (int i = 0; i < 8; ++i) {
    hi[i] = f2bf(x[i]);
    lo[i] = f2bf(x[i] - bf2f(hi[i]));
  }
  uint4 uh, ul;
  uh.x = (unsigned)hi[0] | ((unsigned)hi[1] << 16);
  uh.y = (unsigned)hi[2] | ((unsigned)hi[3] << 16);
  uh.z = (unsigned)hi[4] | ((unsigned)hi[5] << 16);
  uh.w = (unsigned)hi[6] | ((unsigned)hi[7] << 16);
  ul.x = (unsigned)lo[0] | ((unsigned)lo[1] << 16);
  ul.y = (unsigned)lo[2] | ((unsigned)lo[3] << 16);
  ul.z = (unsigned)lo[4] | ((unsigned)lo[5] << 16);
  ul.w = (unsigned)lo[6] | ((unsigned)lo[7] << 16);
  wpk[(size_t)(chunk * 2 + 0) * B_UNITS + u] = uh;
  wpk[(size_t)(chunk * 2 + 1) * B_UNITS + u] = ul;
}

// -------- proj: split-bf16 MFMA GEMM + fused attention partials --------------
__global__ __launch_bounds__(256, 2) void proj_kernel(
    const float* __restrict__ vec,
    const float* __restrict__ wq_b,
    const float* __restrict__ wv_b,
    const float* __restrict__ wsc,     // ws[0] = wkb sum
    const uint4* __restrict__ wpk,     // packed split-bf16 weights
    float* __restrict__ part)          // [B][32][128][17] attn partials
{
  __shared__ uint4 As[2 * A_UNITS];    // hi then lo, 16 KB
  __shared__ uint4 Bs[2 * B_UNITS];    // hi then lo, 40 KB

  const int tid   = threadIdx.x;
  const int lane  = tid & 63;
  const int w     = tid >> 6;          // wave 0..3
  const int wm    = w >> 1;            // wave M half (0/1): rows wm*32..+31
  const int wn    = w & 1;             // wave N half: ntiles wn*5..+4
  const int b     = blockIdx.x >> 5;
  const int jt    = blockIdx.x & 31;
  const int j0    = jt * 64;
  const int col16 = lane & 15;
  const int rbase = (lane >> 4) * 4;

  const float* vecb = vec + (size_t)b * Jn * Hn;
  const bf16x8_t* As8 = (const bf16x8_t*)As;
  const bf16x8_t* Bs8 = (const bf16x8_t*)Bs;

  f32x4_t acc[2][5];
#pragma unroll
  for (int mi = 0; mi < 2; ++mi)
#pragma unroll
    for (int ni = 0; ni < 5; ++ni) acc[mi][ni] = (f32x4_t){0.f, 0.f, 0.f, 0.f};

  for (int chunk = 0; chunk < NCHUNK; ++chunk) {
    const int k0 = chunk * KC;
    // ---- stage A: 2 units/thread, each = 8 consecutive fp32 -> hi+lo bf16x8
#pragma unroll
    for (int rep = 0; rep < 2; ++rep) {
      const int u    = tid + rep * 256;       // 0..511
      const int kblk = u >> 8;
      const int mt   = (u >> 6) & 3;
      const int g    = (u >> 4) & 3;
      const int m    = u & 15;
      const float* src = vecb + (size_t)(j0 + mt * 16 + m) * Hn + k0 + kblk * 32 + g * 8;
      const float4 a0 = *(const float4*)src;
      const float4 a1 = *(const float4*)(src + 4);
      float x[8] = {a0.x, a0.y, a0.z, a0.w, a1.x, a1.y, a1.z, a1.w};
      unsigned short hi[8], lo[8];
#pragma unroll
      for (int i = 0; i < 8; ++i) {
        hi[i] = f2bf(x[i]);
        lo[i] = f2bf(x[i] - bf2f(hi[i]));
      }
      uint4 uh, ul;
      uh.x = (unsigned)hi[0] | ((unsigned)hi[1] << 16);
      uh.y = (unsigned)hi[2] | ((unsigned)hi[3] << 16);
      uh.z = (unsigned)hi[4] | ((unsigned)hi[5] << 16);
      uh.w = (unsigned)hi[6] | ((unsigned)hi[7] << 16);
      ul.x = (unsigned)lo[0] | ((unsigned)lo[1] << 16);
      ul.y = (unsigned)lo[2] | ((unsigned)lo[3] << 16);
      ul.z = (unsigned)lo[4] | ((unsigned)lo[5] << 16);
      ul.w = (unsigned)lo[6] | ((unsigned)lo[7] << 16);
      As[u]           = uh;
      As[A_UNITS + u] = ul;
    }
    // ---- stage B: async global->LDS, 16B/lane, pre-packed linear stream
    {
      const char* gbase = (const char*)wpk + (size_t)chunk * WPK_CHUNK_BYTES + (size_t)lane * 16;
#pragma unroll
      for (int i = 0; i < 10; ++i) {
        const int q = w + i * 4;               // 0..39 wave-instrs of 1 KB
        __builtin_amdgcn_global_load_lds((gvoid_t*)(gbase + q * 1024),
                                         (lvoid_t*)&Bs[q * 64], 16, 0, 0);
      }
    }
    __syncthreads();

#pragma unroll
    for (int kblk = 0; kblk < 2; ++kblk) {
      bf16x8_t bh[5], bl[5];
#pragma unroll
      for (int ni = 0; ni < 5; ++ni) {
        const int idx = (kblk * 10 + wn * 5 + ni) * 64 + lane;
        bh[ni] = Bs8[idx];
        bl[ni] = Bs8[B_UNITS + idx];
      }
#pragma unroll
      for (int mi = 0; mi < 2; ++mi) {
        const int aidx = (kblk * 4 + wm * 2 + mi) * 64 + lane;
        const bf16x8_t ah = As8[aidx];
        const bf16x8_t al = As8[A_UNITS + aidx];
#pragma unroll
        for (int ni = 0; ni < 5; ++ni) {
          acc[mi][ni] = __builtin_amdgcn_mfma_f32_16x16x32_bf16(ah, bh[ni], acc[mi][ni], 0, 0, 0);
          acc[mi][ni] = __builtin_amdgcn_mfma_f32_16x16x32_bf16(ah, bl[ni], acc[mi][ni], 0, 0, 0);
          acc[mi][ni] = __builtin_amdgcn_mfma_f32_16x16x32_bf16(al, bh[ni], acc[mi][ni], 0, 0, 0);
        }
      }
    }
    __syncthreads();
  }

  // ==== fused attention epilogue ====
  // C/D layout: col=lane&15, row=(lane>>4)*4+reg.
  // As reused for ks/v staging; Bs reused for epi[2][128][18] (18.4 KB).
  const float wkb = wsc[0];
  float* ks_s = (float*)&As[0];          // [64]
  float* vt   = ks_s + 64;               // [64][20], rows 16B-aligned (80 B)
  float* epi  = (float*)&Bs[0];          // [2][128][18]

  if (wn == 1) {
    const float vb_ = wv_b[col16];
#pragma unroll
    for (int mi = 0; mi < 2; ++mi) {
      const f32x4_t c = acc[mi][3];      // v columns: n = 128 + col16
#pragma unroll
      for (int r = 0; r < 4; ++r) {
        const int j = (wm * 2 + mi) * 16 + rbase + r;
        vt[j * 20 + col16] = c[r] + vb_;
      }
    }
    if (col16 == 0) {
#pragma unroll
      for (int mi = 0; mi < 2; ++mi) {
        const f32x4_t c = acc[mi][4];    // ksum column: n = 144
#pragma unroll
        for (int r = 0; r < 4; ++r) {
          const int j = (wm * 2 + mi) * 16 + rbase + r;
          ks_s[j] = c[r] + wkb;
        }
      }
    }
  }
  __syncthreads();

  const int NCOL = wn ? 3 : 5;           // q columns this wave owns (uniform)
  float* epiw = epi + wm * 128 * 18;     // this wave's disjoint slab

  // ni-outer, COMPILE-TIME unrolled: po/pz stay scalar registers (no scratch)
#pragma unroll 5
  for (int ni = 0; ni < 5; ++ni) {
    if (ni < NCOL) {
      const float qb = wq_b[(wn * 5 + ni) * 16 + col16];
      float pz = 0.f;
      float po[16];
#pragma unroll
      for (int d = 0; d < 16; ++d) po[d] = 0.f;
#pragma unroll
      for (int mi = 0; mi < 2; ++mi) {
#pragma unroll
        for (int r = 0; r < 4; ++r) {
          const int j = (wm * 2 + mi) * 16 + rbase + r;
          const float ksj = ks_s[j];
          const float4 v0 = *(const float4*)&vt[j * 20];
          const float4 v1 = *(const float4*)&vt[j * 20 + 4];
          const float4 v2 = *(const float4*)&vt[j * 20 + 8];
          const float4 v3 = *(const float4*)&vt[j * 20 + 12];
          const float q   = acc[mi][ni][r] + qb;
          const float e2x = __expf(2.f * q * ksj);
          const float t   = 1.f - 2.f / (e2x + 1.f);
          const float p   = __expf(t);
          pz += p;
          po[0]  += p * v0.x; po[1]  += p * v0.y; po[2]  += p * v0.z; po[3]  += p * v0.w;
          po[4]  += p * v1.x; po[5]  += p * v1.y; po[6]  += p * v1.z; po[7]  += p * v1.w;
          po[8]  += p * v2.x; po[9]  += p * v2.y; po[10] += p * v2.z; po[11] += p * v2.w;
          po[12] += p * v3.x; po[13] += p * v3.y; po[14] += p * v3.z; po[15] += p * v3.w;
        }
      }
      // reduce across lane bits 4,5 (the 4 rbase groups -> this wave's 32 j's)
      pz += __shfl_xor(pz, 16);
      pz += __shfl_xor(pz, 32);
#pragma unroll
      for (int d = 0; d < 16; ++d) {
        po[d] += __shfl_xor(po[d], 16);
        po[d] += __shfl_xor(po[d], 32);
      }
      if (lane < 16) {
        const int n = (wn * 5 + ni) * 16 + lane;
        epiw[n * 18 + 16] = pz;
#pragma unroll
        for (int d = 0; d < 16; ++d) epiw[n * 18 + d] = po[d];
      }
    }
  }
  __syncthreads();
  // coalesced store of [128][17] partial slab (sum of the two wm halves)
  float* pout = part + ((size_t)(b * 32 + jt) * 128) * 17;
  for (int idx = tid; idx < 128 * 17; idx += 256) {
    const int row = idx / 17, c = idx % 17;
    pout[idx] = epi[row * 18 + c] + epi[128 * 18 + row * 18 + c];
  }
}

// -------- finalize: out[b,i,d] = sum_jt O / sum_jt Z ------------------------
__global__ __launch_bounds__(256) void finalize_kernel(const float* __restrict__ part,
                                                       float* __restrict__ out) {
  const int gid = blockIdx.x * 256 + threadIdx.x;   // 0..2047 = (b,i)
  const float* p = part + (size_t)(gid >> 7) * 32 * 128 * 17 + (size_t)(gid & 127) * 17;
  float z = 0.f;
  float o[16];
#pragma unroll
  for (int d = 0; d < 16; ++d) o[d] = 0.f;
  for (int jt = 0; jt < 32; ++jt) {
    const float* pp = p + (size_t)jt * 128 * 17;
    z += pp[16];
#pragma unroll
    for (int d = 0; d < 16; ++d) o[d] += pp[d];
  }
  const float inv = 1.f / z;
  float* dst = out + (size_t)gid * 16;
#pragma unroll
  for (int d = 0; d < 16; ++d) dst[d] = o[d] * inv;
}

// ---------------------------------------------------------------------------
extern "C" void kernel_launch(void* const* d_in, const int* in_sizes, int n_in,
                              void* d_out, int out_size, void* d_ws, size_t ws_size,
                              hipStream_t stream) {
  const float* vec  = (const float*)d_in[0];
  const float* wq_w = (const float*)d_in[1];
  const float* wq_b = (const float*)d_in[2];
  const float* wk_w = (const float*)d_in[3];
  const float* wk_b = (const float*)d_in[4];
  const float* wv_w = (const float*)d_in[5];
  const float* wv_b = (const float*)d_in[6];

  float* ws   = (float*)d_ws;
  uint4* wpk  = (uint4*)(ws + WS_WPK);
  float* part = ws + WS_PART;
  float* out  = (float*)d_out;

  prep1_kernel<<<257, 256, 0, stream>>>(wk_w, wk_b, ws);
  prep2_kernel<<<(NCHUNK * B_UNITS) / 256, 256, 0, stream>>>(wq_w, wv_w, ws, wpk);
  proj_kernel<<<Bn * (Jn / 64), 256, 0, stream>>>(vec, wq_b, wv_b, ws, wpk, part);
  finalize_kernel<<<8, 256, 0, stream>>>(part, out);
}